// Round 3
// baseline (374.504 us; speedup 1.0000x reference)
//
#include <hip/hip_runtime.h>
#include <stdint.h>

// Problem constants (from reference)
#define B_    256
#define NR    64
#define NW    64
#define DIN   512
#define NH    8
#define DK    64
#define E_    512          // NH*DK
#define TEMP_INV 0.125f    // 1/sqrt(64)
#define EPSV  1e-7f

typedef unsigned short u16;
typedef unsigned int   u32;
typedef _Float16 f16;
typedef __attribute__((ext_vector_type(2))) float    floatx2;
typedef __attribute__((ext_vector_type(4))) float    floatx4;
typedef __attribute__((ext_vector_type(4))) u32      uintx4;
typedef __attribute__((ext_vector_type(2))) _Float16 halfx2;
typedef __attribute__((ext_vector_type(8))) _Float16 halfx8;

__device__ __forceinline__ halfx2 h2(u32 u) { union { u32 u; halfx2 h; } c; c.u = u; return c.h; }
// pack two fp32 -> f16x2 dword (RNE via v_cvt_f16_f32 + pack)
__device__ __forceinline__ u32 pkh(float a, float b) {
    union { halfx2 h; u32 u; } c; c.h = (halfx2){(f16)a, (f16)b}; return c.u;
}

// ---------------------------------------------------------------------------
// Kernel 1: grouped projection GEMM, f16 MFMA (fp32 accumulate).
// out[b,e] = sum_d X[b,n,d] * W[n,d,e].  z=0: q->qp  z=1: k->kp  z=2: v->vp
// (vp==nullptr -> legacy atomicAdd-into-vsum fallback for small workspace).
// r7 change vs r6 (THE experiment): OCCUPANCY. r0-r2 showed every pipe <30%
// with OccupancyPercent ~20% (~12 waves/CU cap from ~160 unified regs/wave:
// 96 arch + 64 acc). Latency-targeted fixes (depth-2 prefetch r1, counted
// barrier waits r2) were both null -> the stall is unhidden latency with too
// few waves, fixable only by TLP.
//  * Tile 128x128 -> 64x128 (BM=64, BN=128, BK=32): acc 64->32 regs/thread,
//    LDS 32->24 KB. __launch_bounds__(256,4) enforces >=4 waves/EU
//    (VGPR cap 128) -> >=16 waves/CU, ~1.5-2.5x previous residency.
//  * Grid 8x128x3 = 3072 blocks (12/CU). y = [n0i(2)|nlow(3)|dm(2)], dm
//    fastest: the 4 m-sibling blocks sharing one W[n] 512x128 slice sit at
//    ids spaced 8 -> same XCD (id%8=x preserved), adjacent in dispatch ->
//    W slice fetched once into XCD L2, consumed 4x while hot (per-XCD
//    concurrent W set ~ 8n x 2 slices x 256KB = 4MB ~ L2 size).
// LDS layout scheme unchanged (padding-free, unit-major, all-b128):
//   A: [k-unit u(4)][row r(64)] x 16B      (element k: u=k>>3, j=k&7)
//   B: [k-unit u(4)][e&1][e>>1(64)] x 16B
// Barrier: lgkm-only drain + raw s_barrier (global loads stay in flight).
// ---------------------------------------------------------------------------

#define STORE_A(sbuf) do {                                                    \
        uintx4 ha_ = (uintx4){pkh(pa[0].x, pa[0].y), pkh(pa[0].z, pa[0].w),   \
                              pkh(pa[1].x, pa[1].y), pkh(pa[1].z, pa[1].w)};  \
        *(uintx4*)&As[sbuf][kq8 * 512 + arow * 8] = ha_;                      \
    } while (0)

#define STORE_B(sbuf, pb) do {                                                \
        _Pragma("unroll")                                                     \
        for (int eo = 0; eo < 2; eo++) {                                      \
            uintx4 hv_ = (uintx4){pkh(pb[0][eo], pb[1][eo]),                  \
                                  pkh(pb[2][eo], pb[3][eo]),                  \
                                  pkh(pb[4][eo], pb[5][eo]),                  \
                                  pkh(pb[6][eo], pb[7][eo])};                 \
            *(uintx4*)&Bs[sbuf][kq * 1024 + eo * 512 + p * 8] = hv_;          \
        }                                                                     \
    } while (0)

#define LOAD_A(kn) do {                                                       \
        pa[0] = *(const floatx4*)(aptr + (kn));                               \
        pa[1] = *(const floatx4*)(aptr + (kn) + 4);                           \
    } while (0)

#define LOAD_B(pb, kn) do {                                                   \
        _Pragma("unroll")                                                     \
        for (int j = 0; j < 8; j++)                                           \
            pb[j] = *(const floatx2*)(wptr + (size_t)((kn) + kq*8 + j) * E_); \
    } while (0)

#define COMPUTE(sbuf) do {                                                    \
        halfx8 af_[2], bf_[4];                                                \
        _Pragma("unroll")                                                     \
        for (int mi = 0; mi < 2; mi++)                                        \
            af_[mi] = *(const halfx8*)&As[sbuf][quad*512 + (wm + mi*16 + l15)*8]; \
        _Pragma("unroll")                                                     \
        for (int ni = 0; ni < 4; ni++) {                                      \
            int e_ = wn + ni*16 + l15;                                        \
            bf_[ni] = *(const halfx8*)&Bs[sbuf][quad*1024 + (e_&1)*512 + (e_>>1)*8]; \
        }                                                                     \
        _Pragma("unroll")                                                     \
        for (int mi = 0; mi < 2; mi++)                                        \
            _Pragma("unroll")                                                 \
            for (int ni = 0; ni < 4; ni++)                                    \
                acc[mi][ni] = __builtin_amdgcn_mfma_f32_16x16x32_f16(         \
                    af_[mi], bf_[ni], acc[mi][ni], 0, 0, 0);                  \
    } while (0)

// LDS-only drain + barrier: lgkmcnt(0) covers this wave's ds_reads/ds_writes
// (the dbuf invariant); global loads stay in flight (NO vmcnt drain).
#define PHASE_BARRIER() do {                                                  \
        asm volatile("s_waitcnt lgkmcnt(0)" ::: "memory");                    \
        __builtin_amdgcn_s_barrier();                                         \
        __builtin_amdgcn_sched_barrier(0);                                    \
    } while (0)

__global__ __launch_bounds__(256, 4)
void proj_kernel(const float* __restrict__ q, const float* __restrict__ kk_,
                 const float* __restrict__ v,
                 const float* __restrict__ Wq, const float* __restrict__ Wk,
                 const float* __restrict__ Wv,
                 f16* __restrict__ qp, f16* __restrict__ kp,
                 f16* __restrict__ vp, float* __restrict__ vsum)
{
    const float* X; const float* W; f16* dst;
    if (blockIdx.z == 0)      { X = q;   W = Wq; dst = qp; }
    else if (blockIdx.z == 1) { X = kk_; W = Wk; dst = kp; }
    else                      { X = v;   W = Wv; dst = vp; }

    // y = [n0i(2) | nlow(3) | dm(2)]; id%8 = blockIdx.x = n-octet (XCD key)
    const int n  = blockIdx.x * 8 + ((blockIdx.y >> 2) & 7);
    const int m0 = (blockIdx.y & 3) * 64;
    const int n0 = (blockIdx.y >> 5) * 128;

    __shared__ u16 As[2][2048];   //  8 KB: [u(4)][row(64)][8]
    __shared__ u16 Bs[2][4096];   // 16 KB: [u(4)][e&1][e>>1(64)][8]

    const int tid  = threadIdx.x;
    const int lane = tid & 63;
    const int wave = tid >> 6;
    const int wm   = (wave >> 1) * 32;
    const int wn   = (wave & 1) * 64;
    const int l15  = lane & 15;
    const int quad = lane >> 4;

    floatx4 acc[2][4];
#pragma unroll
    for (int i = 0; i < 2; i++)
#pragma unroll
        for (int j = 0; j < 4; j++) acc[i][j] = (floatx4){0.f, 0.f, 0.f, 0.f};

    // A: thread -> (row 0..63, k-octet 0..3)
    const int arow = tid >> 2;
    const int kq8  = tid & 3;
    const float* aptr = X + ((size_t)(m0 + arow) * NW + n) * DIN + kq8 * 8;
    // B: thread -> 8k x 2e patch; kq == wave
    const int kq = tid >> 6;
    const int p  = tid & 63;
    const float* wptr = W + (size_t)n * (DIN * E_) + n0 + 2 * p;

    floatx4 pa[2];   // A prefetch, depth-1
    floatx2 pb[8];   // B prefetch, depth-1

    LOAD_A(0);
    LOAD_B(pb, 0);

#pragma unroll 1
    for (int it2 = 0; it2 < 8; it2++) {
        const int k0 = it2 * 64;
        // ---- even K-step: buffer 0 ----
        STORE_A(0);
        STORE_B(0, pb);
        LOAD_A(k0 + 32);
        LOAD_B(pb, k0 + 32);
        PHASE_BARRIER();
        COMPUTE(0);
        // ---- odd K-step: buffer 1 ----
        STORE_A(1);
        STORE_B(1, pb);
        if (it2 < 7) { LOAD_A(k0 + 64); LOAD_B(pb, k0 + 64); }
        PHASE_BARRIER();
        COMPUTE(1);
    }

    // Epilogue: C/D layout col = lane&15, row = quad*4 + reg  [measured m89]
    if (dst) {
#pragma unroll
        for (int mi = 0; mi < 2; mi++) {
            int rowb = m0 + wm + mi * 16 + quad * 4;
#pragma unroll
            for (int ni = 0; ni < 4; ni++) {
                int col = n0 + wn + ni * 16 + l15;
#pragma unroll
                for (int r = 0; r < 4; r++)
                    dst[((size_t)(rowb + r) * NW + n) * E_ + col] = (f16)acc[mi][ni][r];
            }
        }
    } else {  // small-workspace fallback: legacy atomic reduction over n
#pragma unroll
        for (int mi = 0; mi < 2; mi++) {
            int rowb = m0 + wm + mi * 16 + quad * 4;
#pragma unroll
            for (int ni = 0; ni < 4; ni++) {
                int col = n0 + wn + ni * 16 + l15;
#pragma unroll
                for (int r = 0; r < 4; r++)
                    atomicAdd(&vsum[(size_t)(rowb + r) * E_ + col], acc[mi][ni][r]);
            }
        }
    }
}

// ---------------------------------------------------------------------------
// Kernel 1b: vsum[b,e] = sum_n vp[b,n,e]   (plain-store replacement for the
// 8.4M device-scope atomics). 16MB read / 512KB write, coalesced u32 loads.
// ---------------------------------------------------------------------------
__global__ __launch_bounds__(256)
void vsum_kernel(const f16* __restrict__ vp, float* __restrict__ vsum)
{
    const int b = blockIdx.x;
    const int t = threadIdx.x;                         // e-pair index (e = 2t, 2t+1)
    const u32* src = (const u32*)vp + (size_t)b * NW * (E_ / 2) + t;
    float s0 = 0.f, s1 = 0.f;
#pragma unroll 4
    for (int nn = 0; nn < NW; nn++) {
        halfx2 hv = h2(src[(size_t)nn * (E_ / 2)]);
        s0 += (float)hv.x;
        s1 += (float)hv.y;
    }
    *(floatx2*)&vsum[(size_t)b * E_ + 2 * t] = (floatx2){s0, s1};
}

// ---------------------------------------------------------------------------
// Kernel 2: per-(h,b) scores via MFMA. scores(64x64, K=64) = qh @ kh^T.
// LDS rows padded +8 f16 (stride 72) -> fragment b128 reads 2-way (free).
// Wave w owns score rows w*16..w*16+15; row-max via 16-lane shuffle reduce.
// Then wave 0: double-exp softmax over 64 rows + top-16 threshold.
// ---------------------------------------------------------------------------
__global__ __launch_bounds__(256)
void attn_kernel(const f16* __restrict__ qp, const f16* __restrict__ kp,
                 float* __restrict__ attnT)
{
    const int h = blockIdx.x >> 8;
    const int b = blockIdx.x & 255;
    __shared__ u16 qs[64 * 72];
    __shared__ u16 ks[64 * 72];
    __shared__ float ms[64];

    const int t    = threadIdx.x;
    const int w    = t >> 6;
    const int lane = t & 63;
    const int l15  = lane & 15;
    const int quad = lane >> 4;

    {   // stage q/k slices: 4 threads per row, 32B each (2x b128)
        const int r = t >> 2, c = t & 3;
        const f16* qsrc = qp + ((size_t)(b * NR + r)) * E_ + h * DK + c * 16;
        const f16* ksrc = kp + ((size_t)(b * NW + r)) * E_ + h * DK + c * 16;
        *(uintx4*)&qs[r * 72 + c * 16]     = *(const uintx4*)(qsrc);
        *(uintx4*)&qs[r * 72 + c * 16 + 8] = *(const uintx4*)(qsrc + 8);
        *(uintx4*)&ks[r * 72 + c * 16]     = *(const uintx4*)(ksrc);
        *(uintx4*)&ks[r * 72 + c * 16 + 8] = *(const uintx4*)(ksrc + 8);
    }
    __syncthreads();

    floatx4 sc[4];
#pragma unroll
    for (int ni = 0; ni < 4; ni++) sc[ni] = (floatx4){0.f, 0.f, 0.f, 0.f};

    halfx8 af[2];
#pragma unroll
    for (int kk = 0; kk < 2; kk++)
        af[kk] = *(const halfx8*)&qs[(w * 16 + l15) * 72 + kk * 32 + quad * 8];
#pragma unroll
    for (int ni = 0; ni < 4; ni++)
#pragma unroll
        for (int kk = 0; kk < 2; kk++) {
            halfx8 bf = *(const halfx8*)&ks[(ni * 16 + l15) * 72 + kk * 32 + quad * 8];
            sc[ni] = __builtin_amdgcn_mfma_f32_16x16x32_f16(af[kk], bf, sc[ni], 0, 0, 0);
        }

    // row-max: D layout col=l15, row=quad*4+r -> reduce over ni (VALU) + l15 (shfl)
#pragma unroll
    for (int r = 0; r < 4; r++) {
        float rm = fmaxf(fmaxf(sc[0][r], sc[1][r]), fmaxf(sc[2][r], sc[3][r]));
#pragma unroll
        for (int d = 1; d < 16; d <<= 1) rm = fmaxf(rm, __shfl_xor(rm, d));
        if (l15 == 0) ms[w * 16 + quad * 4 + r] = rm;
    }
    __syncthreads();

    if (t < 64) {   // wave 0 only
        float mm = ms[lane] * TEMP_INV;
        float e = expf(mm);                      // a = exp(max score)
        float mx = e;
#pragma unroll
        for (int d = 1; d < 64; d <<= 1) mx = fmaxf(mx, __shfl_xor(mx, d));
        float tt = expf(e - mx);
        float S = tt;
#pragma unroll
        for (int d = 1; d < 64; d <<= 1) S += __shfl_xor(S, d);
        float s = tt / S;

        // k-th largest (k=16) via 16x (wave-max, mask first holder)
        float cur = s, v16 = 0.f;
        for (int itk = 0; itk < 16; itk++) {
            float mv = cur;
#pragma unroll
            for (int d = 1; d < 64; d <<= 1) mv = fmaxf(mv, __shfl_xor(mv, d));
            unsigned long long bal = __ballot(cur == mv);
            int first = __ffsll(bal) - 1;
            if (lane == first) cur = -1e30f;
            v16 = mv;
        }
        float delta = v16 + EPSV;
        float ww = fmaxf(s - delta, 0.f);
        float sw = ww;
#pragma unroll
        for (int d = 1; d < 64; d <<= 1) sw += __shfl_xor(sw, d);
        attnT[((size_t)b * NR + lane) * NH + h] = ww / (sw + EPSV);
    }
}

// ---------------------------------------------------------------------------
// Kernel 3: fcv[b,h,o] = sum_dv vsum[b, h*64+dv] * W[o, h*64+dv]
// grid (16: ohalf*8+bq, 8: h, 2: fc/gate)   [UNCHANGED]
// ---------------------------------------------------------------------------
__global__ __launch_bounds__(256)
void fcv_kernel(const float* __restrict__ vsum, const float* __restrict__ fc_w,
                const float* __restrict__ gate_w, float* __restrict__ fcv,
                float* __restrict__ gatev)
{
    const int ohalf = blockIdx.x >> 3;
    const int bq    = blockIdx.x & 7;
    const int h     = blockIdx.y;
    const float* W  = blockIdx.z ? gate_w : fc_w;
    float* out      = blockIdx.z ? gatev : fcv;
    const int o     = ohalf * 256 + threadIdx.x;

    __shared__ float vs[32 * 64];
#pragma unroll
    for (int i = 0; i < 8; i++) {
        int idx = i * 256 + threadIdx.x;
        int bb = idx >> 6, d = idx & 63;
        vs[idx] = vsum[(size_t)(bq * 32 + bb) * E_ + h * DK + d];
    }
    floatx4 wr[16];
#pragma unroll
    for (int c = 0; c < 16; c++)
        wr[c] = *(const floatx4*)(W + (size_t)o * E_ + h * DK + c * 4);
    __syncthreads();

    for (int bb = 0; bb < 32; bb++) {
        const floatx4* vr = (const floatx4*)&vs[bb * 64];
        float a = 0.f;
#pragma unroll
        for (int c = 0; c < 16; c++) {
            floatx4 vv = vr[c];
            a += vv.x * wr[c].x + vv.y * wr[c].y + vv.z * wr[c].z + vv.w * wr[c].w;
        }
        out[((size_t)(bq * 32 + bb) * NH + h) * E_ + o] = a;
    }
}

// ---------------------------------------------------------------------------
// Kernel 4: out[b,r,o] = sigmoid(gate_lin) * tanh(fc_lin)
// grid 256x4 (16 rows per block).
// ---------------------------------------------------------------------------
__global__ __launch_bounds__(256)
void final_kernel(const float* __restrict__ fcv, const float* __restrict__ gatev,
                  const float* __restrict__ attnT, const float* __restrict__ fc_b,
                  const float* __restrict__ gate_b, float* __restrict__ out)
{
    const int b   = blockIdx.x;
    const int r0  = blockIdx.y * 16;
    const int tid = threadIdx.x;
    __shared__ float ats[16 * NH];

    if (tid < 16 * NH) ats[tid] = attnT[(size_t)b * NR * NH + r0 * NH + tid];

    float fr[2][8], gr[2][8];
#pragma unroll
    for (int half = 0; half < 2; half++) {
        int o = half * 256 + tid;
#pragma unroll
        for (int hh = 0; hh < 8; hh++) {
            fr[half][hh] = fcv[((size_t)b * NH + hh) * E_ + o];
            gr[half][hh] = gatev[((size_t)b * NH + hh) * E_ + o];
        }
    }
    float bfc0 = fc_b[tid],   bfc1 = fc_b[256 + tid];
    float bgt0 = gate_b[tid], bgt1 = gate_b[256 + tid];
    __syncthreads();

    for (int r = 0; r < 16; r++) {
        float a[8];
#pragma unroll
        for (int hh = 0; hh < 8; hh++) a[hh] = ats[r * NH + hh];
#pragma unroll
        for (int half = 0; half < 2; half++) {
            int o = half * 256 + tid;
            float fc = half ? bfc1 : bfc0;
            float gt = half ? bgt1 : bgt0;
#pragma unroll
            for (int hh = 0; hh < 8; hh++) {
                fc = fmaf(a[hh], fr[half][hh], fc);
                gt = fmaf(a[hh], gr[half][hh], gt);
            }
            float g  = 1.f / (1.f + __expf(-gt));
            float e2 = __expf(2.f * fc);
            float th = 1.f - 2.f / (e2 + 1.f);
            out[((size_t)(b * NR + r0 + r)) * E_ + o] = g * th;
        }
    }
}

// ---------------------------------------------------------------------------
extern "C" void kernel_launch(void* const* d_in, const int* in_sizes, int n_in,
                              void* d_out, int out_size, void* d_ws, size_t ws_size,
                              hipStream_t stream)
{
    const float* q      = (const float*)d_in[0];
    const float* k      = (const float*)d_in[1];
    const float* v      = (const float*)d_in[2];
    const float* Wq     = (const float*)d_in[3];
    const float* Wk     = (const float*)d_in[4];
    const float* Wv     = (const float*)d_in[5];
    const float* fc_w   = (const float*)d_in[6];
    const float* fc_b   = (const float*)d_in[7];
    const float* gate_w = (const float*)d_in[8];
    const float* gate_b = (const float*)d_in[9];
    float* out = (float*)d_out;

    char* ws = (char*)d_ws;
    f16* qp = (f16*)(ws);                          // 16 MB
    f16* kp = (f16*)(ws + (16u << 20));            // 16 MB

    const bool big = ws_size >= (50u << 20);
    f16* vp; float* vsum; float* attnT; float* fcv; float* gatev;
    if (big) {
        vp    = (f16*)(ws + (32u << 20));                    // 16 MB (dead after vsum_kernel)
        vsum  = (float*)(ws + (48u << 20));                  // 512 KB
        attnT = (float*)(ws + (48u << 20) + 524288);         // 512 KB
        fcv   = (float*)(ws + (32u << 20));                  // 4 MB, overlaps vp (written later)
        gatev = (float*)(ws + (36u << 20));                  // 4 MB, overlaps vp
    } else {   // legacy 42MB layout + atomic v-reduction
        vp    = nullptr;
        vsum  = (float*)(ws + 33554432);
        attnT = (float*)(ws + 33554432 + 524288);
        fcv   = (float*)(ws + 33554432 + 2 * 524288);
        gatev = (float*)(ws + 33554432 + 2 * 524288 + 4194304);
        hipMemsetAsync(vsum, 0, 524288, stream);
    }

    hipLaunchKernelGGL(proj_kernel, dim3(8, 128, 3), dim3(256), 0, stream,
                       q, k, v, Wq, Wk, Wv, qp, kp, vp, vsum);
    hipLaunchKernelGGL(attn_kernel, dim3(2048), dim3(256), 0, stream, qp, kp, attnT);
    if (big)
        hipLaunchKernelGGL(vsum_kernel, dim3(256), dim3(256), 0, stream, vp, vsum);
    hipLaunchKernelGGL(fcv_kernel, dim3(16, 8, 2), dim3(256), 0, stream,
                       vsum, fc_w, gate_w, fcv, gatev);
    hipLaunchKernelGGL(final_kernel, dim3(256, 4), dim3(256), 0, stream,
                       fcv, gatev, attnT, fc_b, gate_b, out);
}

// Round 4
// 353.116 us; speedup vs baseline: 1.0606x; 1.0606x over previous
//
#include <hip/hip_runtime.h>
#include <stdint.h>

// Problem constants (from reference)
#define B_    256
#define NR    64
#define NW    64
#define DIN   512
#define NH    8
#define DK    64
#define E_    512          // NH*DK
#define TEMP_INV 0.125f    // 1/sqrt(64)
#define EPSV  1e-7f

typedef unsigned short u16;
typedef unsigned int   u32;
typedef _Float16 f16;
typedef __attribute__((ext_vector_type(2))) float    floatx2;
typedef __attribute__((ext_vector_type(4))) float    floatx4;
typedef __attribute__((ext_vector_type(4))) u32      uintx4;
typedef __attribute__((ext_vector_type(2))) _Float16 halfx2;
typedef __attribute__((ext_vector_type(8))) _Float16 halfx8;

__device__ __forceinline__ halfx2 h2(u32 u) { union { u32 u; halfx2 h; } c; c.u = u; return c.h; }
// pack two fp32 -> f16x2 dword (RNE via v_cvt_f16_f32 + pack)
__device__ __forceinline__ u32 pkh(float a, float b) {
    union { halfx2 h; u32 u; } c; c.h = (halfx2){(f16)a, (f16)b}; return c.u;
}

// ---------------------------------------------------------------------------
// Kernel 1: grouped projection GEMM, f16 MFMA (fp32 accumulate).
// out[b,e] = sum_d X[b,n,d] * W[n,d,e].  z=0: q->qp  z=1: k->kp  z=2: v->vp
// (vp==nullptr -> legacy atomicAdd-into-vsum fallback for small workspace).
// r8 change vs r2-base (THE experiment): A-stream depth-2 prefetch.
// Evidence r0-r3: per-block K-step constant ~5000-5500cy regardless of
// barrier type (r2) or 2x occupancy (r3); issue work only ~600cy -> each
// step serializes one congestion-inflated load latency. r1/r2 gave B
// full-iteration slack but A only ~250cy (barrier+COMPUTE) -> A-stall set
// the step time; step = max-stream-stall explains r0==r1==r2.
//  * pa0/pa1 double-buffer: EVERY load (A and B) now issued 2 K-steps
//    before its counted-vmcnt use; slack ~2 steps > congested latency.
//  * __launch_bounds__(256,2): +16 VGPR staging (~176 unified) caps at
//    2 waves/SIMD -- no real loss, r2's measured residency was already
//    ~6.5 waves/CU (< 2/SIMD cap).
// Tile 128x128 (r2 base: best FETCH 190MB, conflicts 3.1M). Barrier is
// lgkm-only drain + raw s_barrier (global loads live across barriers).
// LDS layout unchanged (padding-free, unit-major, all-b128):
//   A: [k-unit u(4)][row r(128)] x 16B      (element k: u=k>>3, j=k&7)
//   B: [k-unit u(4)][e&1][e>>1(64)] x 16B
// XCD swizzle: all 8 tiles of (n,z) share blockIdx-linear % 8 -> same XCD.
// ---------------------------------------------------------------------------

#define STORE_A(sbuf, pa) do {                                                \
        u32 hh_[8];                                                           \
        _Pragma("unroll")                                                     \
        for (int c = 0; c < 4; c++) {                                         \
            hh_[2*c]   = pkh(pa[c].x, pa[c].y);                               \
            hh_[2*c+1] = pkh(pa[c].z, pa[c].w);                               \
        }                                                                     \
        *(uintx4*)&As[sbuf][(2*ahalf+0)*1024 + arow*8] =                      \
            (uintx4){hh_[0],hh_[1],hh_[2],hh_[3]};                            \
        *(uintx4*)&As[sbuf][(2*ahalf+1)*1024 + arow*8] =                      \
            (uintx4){hh_[4],hh_[5],hh_[6],hh_[7]};                            \
    } while (0)

#define STORE_B(sbuf, pb) do {                                                \
        _Pragma("unroll")                                                     \
        for (int eo = 0; eo < 2; eo++) {                                      \
            uintx4 hv_ = (uintx4){pkh(pb[0][eo], pb[1][eo]),                  \
                                  pkh(pb[2][eo], pb[3][eo]),                  \
                                  pkh(pb[4][eo], pb[5][eo]),                  \
                                  pkh(pb[6][eo], pb[7][eo])};                 \
            *(uintx4*)&Bs[sbuf][kq * 1024 + eo * 512 + p * 8] = hv_;          \
        }                                                                     \
    } while (0)

#define LOAD_A(pa, kn) do {                                                   \
        _Pragma("unroll")                                                     \
        for (int c = 0; c < 4; c++)                                           \
            pa[c] = *(const floatx4*)(aptr + (kn) + c * 4);                   \
    } while (0)

#define LOAD_B(pb, kn) do {                                                   \
        _Pragma("unroll")                                                     \
        for (int j = 0; j < 8; j++)                                           \
            pb[j] = *(const floatx2*)(wptr + (size_t)((kn) + kq*8 + j) * E_); \
    } while (0)

#define COMPUTE(sbuf) do {                                                    \
        halfx8 af_[4], bf_[4];                                                \
        _Pragma("unroll")                                                     \
        for (int mi = 0; mi < 4; mi++)                                        \
            af_[mi] = *(const halfx8*)&As[sbuf][quad*1024 + (wm + mi*16 + l15)*8]; \
        _Pragma("unroll")                                                     \
        for (int ni = 0; ni < 4; ni++) {                                      \
            int e_ = wn + ni*16 + l15;                                        \
            bf_[ni] = *(const halfx8*)&Bs[sbuf][quad*1024 + (e_&1)*512 + (e_>>1)*8]; \
        }                                                                     \
        _Pragma("unroll")                                                     \
        for (int mi = 0; mi < 4; mi++)                                        \
            _Pragma("unroll")                                                 \
            for (int ni = 0; ni < 4; ni++)                                    \
                acc[mi][ni] = __builtin_amdgcn_mfma_f32_16x16x32_f16(         \
                    af_[mi], bf_[ni], acc[mi][ni], 0, 0, 0);                  \
    } while (0)

// LDS-only drain + barrier: lgkmcnt(0) covers this wave's ds_reads/ds_writes
// (the dbuf invariant); global loads stay in flight (NO vmcnt drain).
#define PHASE_BARRIER() do {                                                  \
        asm volatile("s_waitcnt lgkmcnt(0)" ::: "memory");                    \
        __builtin_amdgcn_s_barrier();                                         \
        __builtin_amdgcn_sched_barrier(0);                                    \
    } while (0)

__global__ __launch_bounds__(256, 2)
void proj_kernel(const float* __restrict__ q, const float* __restrict__ kk_,
                 const float* __restrict__ v,
                 const float* __restrict__ Wq, const float* __restrict__ Wk,
                 const float* __restrict__ Wv,
                 f16* __restrict__ qp, f16* __restrict__ kp,
                 f16* __restrict__ vp, float* __restrict__ vsum)
{
    const float* X; const float* W; f16* dst;
    if (blockIdx.z == 0)      { X = q;   W = Wq; dst = qp; }
    else if (blockIdx.z == 1) { X = kk_; W = Wk; dst = kp; }
    else                      { X = v;   W = Wv; dst = vp; }

    // XCD-locality remap: n determines id%8; t_ = tile (m0,n0)
    const int n  = blockIdx.x * 8 + (blockIdx.y & 7);
    const int t_ = blockIdx.y >> 3;
    const int m0 = (t_ >> 2) * 128;
    const int n0 = (t_ & 3) * 128;

    __shared__ u16 As[2][4096];
    __shared__ u16 Bs[2][4096];

    const int tid  = threadIdx.x;
    const int lane = tid & 63;
    const int wave = tid >> 6;
    const int wm   = (wave >> 1) * 64;
    const int wn   = (wave & 1) * 64;
    const int l15  = lane & 15;
    const int quad = lane >> 4;

    floatx4 acc[4][4];
#pragma unroll
    for (int i = 0; i < 4; i++)
#pragma unroll
        for (int j = 0; j < 4; j++) acc[i][j] = (floatx4){0.f, 0.f, 0.f, 0.f};

    // A: thread -> (row, k-half of 16)
    const int arow  = tid >> 1;
    const int ahalf = tid & 1;
    const float* aptr = X + ((size_t)(m0 + arow) * NW + n) * DIN + ahalf * 16;
    // B: thread -> 8k x 2e patch; kq == wave
    const int kq = tid >> 6;
    const int p  = tid & 63;
    const float* wptr = W + (size_t)n * (DIN * E_) + n0 + 2 * p;

    floatx4 pa0[4], pa1[4];  // A prefetch, depth-2 (even / odd K-steps)
    floatx2 pb0[8], pb1[8];  // B prefetch, depth-2 (even / odd K-steps)

    LOAD_A(pa0, 0);
    LOAD_A(pa1, 32);
    LOAD_B(pb0, 0);
    LOAD_B(pb1, 32);

#pragma unroll 1
    for (int it2 = 0; it2 < 8; it2++) {
        const int k0 = it2 * 64;
        // ---- even K-step: buffer 0 ----
        STORE_A(0, pa0);             // pa0 issued a full it2 ago: slack ~2 steps
        STORE_B(0, pb0);
        if (it2 < 7) { LOAD_A(pa0, k0 + 64); LOAD_B(pb0, k0 + 64); }
        PHASE_BARRIER();
        COMPUTE(0);
        // ---- odd K-step: buffer 1 ----
        STORE_A(1, pa1);             // pa1 issued a full it2 ago: slack ~2 steps
        STORE_B(1, pb1);
        if (it2 < 7) { LOAD_A(pa1, k0 + 96); LOAD_B(pb1, k0 + 96); }
        PHASE_BARRIER();
        COMPUTE(1);
    }

    // Epilogue: C/D layout col = lane&15, row = quad*4 + reg  [measured m89]
    if (dst) {
#pragma unroll
        for (int mi = 0; mi < 4; mi++) {
            int rowb = m0 + wm + mi * 16 + quad * 4;
#pragma unroll
            for (int ni = 0; ni < 4; ni++) {
                int col = n0 + wn + ni * 16 + l15;
#pragma unroll
                for (int r = 0; r < 4; r++)
                    dst[((size_t)(rowb + r) * NW + n) * E_ + col] = (f16)acc[mi][ni][r];
            }
        }
    } else {  // small-workspace fallback: legacy atomic reduction over n
#pragma unroll
        for (int mi = 0; mi < 4; mi++) {
            int rowb = m0 + wm + mi * 16 + quad * 4;
#pragma unroll
            for (int ni = 0; ni < 4; ni++) {
                int col = n0 + wn + ni * 16 + l15;
#pragma unroll
                for (int r = 0; r < 4; r++)
                    atomicAdd(&vsum[(size_t)(rowb + r) * E_ + col], acc[mi][ni][r]);
            }
        }
    }
}

// ---------------------------------------------------------------------------
// Kernel 1b: vsum[b,e] = sum_n vp[b,n,e]   (plain-store replacement for the
// 8.4M device-scope atomics). 16MB read / 512KB write, coalesced u32 loads.
// ---------------------------------------------------------------------------
__global__ __launch_bounds__(256)
void vsum_kernel(const f16* __restrict__ vp, float* __restrict__ vsum)
{
    const int b = blockIdx.x;
    const int t = threadIdx.x;                         // e-pair index (e = 2t, 2t+1)
    const u32* src = (const u32*)vp + (size_t)b * NW * (E_ / 2) + t;
    float s0 = 0.f, s1 = 0.f;
#pragma unroll 4
    for (int nn = 0; nn < NW; nn++) {
        halfx2 hv = h2(src[(size_t)nn * (E_ / 2)]);
        s0 += (float)hv.x;
        s1 += (float)hv.y;
    }
    *(floatx2*)&vsum[(size_t)b * E_ + 2 * t] = (floatx2){s0, s1};
}

// ---------------------------------------------------------------------------
// Kernel 2: per-(h,b) scores via MFMA. scores(64x64, K=64) = qh @ kh^T.
// LDS rows padded +8 f16 (stride 72) -> fragment b128 reads 2-way (free).
// Wave w owns score rows w*16..w*16+15; row-max via 16-lane shuffle reduce.
// Then wave 0: double-exp softmax over 64 rows + top-16 threshold.
// ---------------------------------------------------------------------------
__global__ __launch_bounds__(256)
void attn_kernel(const f16* __restrict__ qp, const f16* __restrict__ kp,
                 float* __restrict__ attnT)
{
    const int h = blockIdx.x >> 8;
    const int b = blockIdx.x & 255;
    __shared__ u16 qs[64 * 72];
    __shared__ u16 ks[64 * 72];
    __shared__ float ms[64];

    const int t    = threadIdx.x;
    const int w    = t >> 6;
    const int lane = t & 63;
    const int l15  = lane & 15;
    const int quad = lane >> 4;

    {   // stage q/k slices: 4 threads per row, 32B each (2x b128)
        const int r = t >> 2, c = t & 3;
        const f16* qsrc = qp + ((size_t)(b * NR + r)) * E_ + h * DK + c * 16;
        const f16* ksrc = kp + ((size_t)(b * NW + r)) * E_ + h * DK + c * 16;
        *(uintx4*)&qs[r * 72 + c * 16]     = *(const uintx4*)(qsrc);
        *(uintx4*)&qs[r * 72 + c * 16 + 8] = *(const uintx4*)(qsrc + 8);
        *(uintx4*)&ks[r * 72 + c * 16]     = *(const uintx4*)(ksrc);
        *(uintx4*)&ks[r * 72 + c * 16 + 8] = *(const uintx4*)(ksrc + 8);
    }
    __syncthreads();

    floatx4 sc[4];
#pragma unroll
    for (int ni = 0; ni < 4; ni++) sc[ni] = (floatx4){0.f, 0.f, 0.f, 0.f};

    halfx8 af[2];
#pragma unroll
    for (int kk = 0; kk < 2; kk++)
        af[kk] = *(const halfx8*)&qs[(w * 16 + l15) * 72 + kk * 32 + quad * 8];
#pragma unroll
    for (int ni = 0; ni < 4; ni++)
#pragma unroll
        for (int kk = 0; kk < 2; kk++) {
            halfx8 bf = *(const halfx8*)&ks[(ni * 16 + l15) * 72 + kk * 32 + quad * 8];
            sc[ni] = __builtin_amdgcn_mfma_f32_16x16x32_f16(af[kk], bf, sc[ni], 0, 0, 0);
        }

    // row-max: D layout col=l15, row=quad*4+r -> reduce over ni (VALU) + l15 (shfl)
#pragma unroll
    for (int r = 0; r < 4; r++) {
        float rm = fmaxf(fmaxf(sc[0][r], sc[1][r]), fmaxf(sc[2][r], sc[3][r]));
#pragma unroll
        for (int d = 1; d < 16; d <<= 1) rm = fmaxf(rm, __shfl_xor(rm, d));
        if (l15 == 0) ms[w * 16 + quad * 4 + r] = rm;
    }
    __syncthreads();

    if (t < 64) {   // wave 0 only
        float mm = ms[lane] * TEMP_INV;
        float e = expf(mm);                      // a = exp(max score)
        float mx = e;
#pragma unroll
        for (int d = 1; d < 64; d <<= 1) mx = fmaxf(mx, __shfl_xor(mx, d));
        float tt = expf(e - mx);
        float S = tt;
#pragma unroll
        for (int d = 1; d < 64; d <<= 1) S += __shfl_xor(S, d);
        float s = tt / S;

        // k-th largest (k=16) via 16x (wave-max, mask first holder)
        float cur = s, v16 = 0.f;
        for (int itk = 0; itk < 16; itk++) {
            float mv = cur;
#pragma unroll
            for (int d = 1; d < 64; d <<= 1) mv = fmaxf(mv, __shfl_xor(mv, d));
            unsigned long long bal = __ballot(cur == mv);
            int first = __ffsll(bal) - 1;
            if (lane == first) cur = -1e30f;
            v16 = mv;
        }
        float delta = v16 + EPSV;
        float ww = fmaxf(s - delta, 0.f);
        float sw = ww;
#pragma unroll
        for (int d = 1; d < 64; d <<= 1) sw += __shfl_xor(sw, d);
        attnT[((size_t)b * NR + lane) * NH + h] = ww / (sw + EPSV);
    }
}

// ---------------------------------------------------------------------------
// Kernel 3: fcv[b,h,o] = sum_dv vsum[b, h*64+dv] * W[o, h*64+dv]
// grid (16: ohalf*8+bq, 8: h, 2: fc/gate)   [UNCHANGED]
// ---------------------------------------------------------------------------
__global__ __launch_bounds__(256)
void fcv_kernel(const float* __restrict__ vsum, const float* __restrict__ fc_w,
                const float* __restrict__ gate_w, float* __restrict__ fcv,
                float* __restrict__ gatev)
{
    const int ohalf = blockIdx.x >> 3;
    const int bq    = blockIdx.x & 7;
    const int h     = blockIdx.y;
    const float* W  = blockIdx.z ? gate_w : fc_w;
    float* out      = blockIdx.z ? gatev : fcv;
    const int o     = ohalf * 256 + threadIdx.x;

    __shared__ float vs[32 * 64];
#pragma unroll
    for (int i = 0; i < 8; i++) {
        int idx = i * 256 + threadIdx.x;
        int bb = idx >> 6, d = idx & 63;
        vs[idx] = vsum[(size_t)(bq * 32 + bb) * E_ + h * DK + d];
    }
    floatx4 wr[16];
#pragma unroll
    for (int c = 0; c < 16; c++)
        wr[c] = *(const floatx4*)(W + (size_t)o * E_ + h * DK + c * 4);
    __syncthreads();

    for (int bb = 0; bb < 32; bb++) {
        const floatx4* vr = (const floatx4*)&vs[bb * 64];
        float a = 0.f;
#pragma unroll
        for (int c = 0; c < 16; c++) {
            floatx4 vv = vr[c];
            a += vv.x * wr[c].x + vv.y * wr[c].y + vv.z * wr[c].z + vv.w * wr[c].w;
        }
        out[((size_t)(bq * 32 + bb) * NH + h) * E_ + o] = a;
    }
}

// ---------------------------------------------------------------------------
// Kernel 4: out[b,r,o] = sigmoid(gate_lin) * tanh(fc_lin)
// grid 256x4 (16 rows per block).
// ---------------------------------------------------------------------------
__global__ __launch_bounds__(256)
void final_kernel(const float* __restrict__ fcv, const float* __restrict__ gatev,
                  const float* __restrict__ attnT, const float* __restrict__ fc_b,
                  const float* __restrict__ gate_b, float* __restrict__ out)
{
    const int b   = blockIdx.x;
    const int r0  = blockIdx.y * 16;
    const int tid = threadIdx.x;
    __shared__ float ats[16 * NH];

    if (tid < 16 * NH) ats[tid] = attnT[(size_t)b * NR * NH + r0 * NH + tid];

    float fr[2][8], gr[2][8];
#pragma unroll
    for (int half = 0; half < 2; half++) {
        int o = half * 256 + tid;
#pragma unroll
        for (int hh = 0; hh < 8; hh++) {
            fr[half][hh] = fcv[((size_t)b * NH + hh) * E_ + o];
            gr[half][hh] = gatev[((size_t)b * NH + hh) * E_ + o];
        }
    }
    float bfc0 = fc_b[tid],   bfc1 = fc_b[256 + tid];
    float bgt0 = gate_b[tid], bgt1 = gate_b[256 + tid];
    __syncthreads();

    for (int r = 0; r < 16; r++) {
        float a[8];
#pragma unroll
        for (int hh = 0; hh < 8; hh++) a[hh] = ats[r * NH + hh];
#pragma unroll
        for (int half = 0; half < 2; half++) {
            int o = half * 256 + tid;
            float fc = half ? bfc1 : bfc0;
            float gt = half ? bgt1 : bgt0;
#pragma unroll
            for (int hh = 0; hh < 8; hh++) {
                fc = fmaf(a[hh], fr[half][hh], fc);
                gt = fmaf(a[hh], gr[half][hh], gt);
            }
            float g  = 1.f / (1.f + __expf(-gt));
            float e2 = __expf(2.f * fc);
            float th = 1.f - 2.f / (e2 + 1.f);
            out[((size_t)(b * NR + r0 + r)) * E_ + o] = g * th;
        }
    }
}

// ---------------------------------------------------------------------------
extern "C" void kernel_launch(void* const* d_in, const int* in_sizes, int n_in,
                              void* d_out, int out_size, void* d_ws, size_t ws_size,
                              hipStream_t stream)
{
    const float* q      = (const float*)d_in[0];
    const float* k      = (const float*)d_in[1];
    const float* v      = (const float*)d_in[2];
    const float* Wq     = (const float*)d_in[3];
    const float* Wk     = (const float*)d_in[4];
    const float* Wv     = (const float*)d_in[5];
    const float* fc_w   = (const float*)d_in[6];
    const float* fc_b   = (const float*)d_in[7];
    const float* gate_w = (const float*)d_in[8];
    const float* gate_b = (const float*)d_in[9];
    float* out = (float*)d_out;

    char* ws = (char*)d_ws;
    f16* qp = (f16*)(ws);                          // 16 MB
    f16* kp = (f16*)(ws + (16u << 20));            // 16 MB

    const bool big = ws_size >= (50u << 20);
    f16* vp; float* vsum; float* attnT; float* fcv; float* gatev;
    if (big) {
        vp    = (f16*)(ws + (32u << 20));                    // 16 MB (dead after vsum_kernel)
        vsum  = (float*)(ws + (48u << 20));                  // 512 KB
        attnT = (float*)(ws + (48u << 20) + 524288);         // 512 KB
        fcv   = (float*)(ws + (32u << 20));                  // 4 MB, overlaps vp (written later)
        gatev = (float*)(ws + (36u << 20));                  // 4 MB, overlaps vp
    } else {   // legacy 42MB layout + atomic v-reduction
        vp    = nullptr;
        vsum  = (float*)(ws + 33554432);
        attnT = (float*)(ws + 33554432 + 524288);
        fcv   = (float*)(ws + 33554432 + 2 * 524288);
        gatev = (float*)(ws + 33554432 + 2 * 524288 + 4194304);
        hipMemsetAsync(vsum, 0, 524288, stream);
    }

    hipLaunchKernelGGL(proj_kernel, dim3(8, 64, 3), dim3(256), 0, stream,
                       q, k, v, Wq, Wk, Wv, qp, kp, vp, vsum);
    hipLaunchKernelGGL(attn_kernel, dim3(2048), dim3(256), 0, stream, qp, kp, attnT);
    if (big)
        hipLaunchKernelGGL(vsum_kernel, dim3(256), dim3(256), 0, stream, vp, vsum);
    hipLaunchKernelGGL(fcv_kernel, dim3(16, 8, 2), dim3(256), 0, stream,
                       vsum, fc_w, gate_w, fcv, gatev);
    hipLaunchKernelGGL(final_kernel, dim3(256, 4), dim3(256), 0, stream,
                       fcv, gatev, attnT, fc_b, gate_b, out);
}